// Round 9
// baseline (10567.476 us; speedup 1.0000x reference)
//
#include <hip/hip_runtime.h>
#include <hip/hip_fp16.h>

// Problem constants
#define BB 64
#define TT 2048
#define II 128
#define HH 128
#define NG 512   // 4*H
#define SLOTS 64
#define PAYW 384 // payload words per slot: pg_i[128] pg_f[128] h0[128]

typedef _Float16 h2_t __attribute__((ext_vector_type(2)));

#if defined(__has_builtin)
#if __has_builtin(__builtin_amdgcn_fdot2)
#define HAVE_FDOT2 1
#endif
#endif

__device__ __forceinline__ float fdot2f(h2_t a, h2_t b, float c) {
#ifdef HAVE_FDOT2
  return __builtin_amdgcn_fdot2(a, b, c, false);
#else
  return c + (float)a[0] * (float)b[0] + (float)a[1] * (float)b[1];
#endif
}

__device__ __forceinline__ float fast_sigmoid(float x) {
  float t = __builtin_amdgcn_exp2f(-1.4426950408889634f * x);
  return __builtin_amdgcn_rcpf(1.0f + t);
}
__device__ __forceinline__ float act_gate(float x, bool tanh_sel) {
  float xx = tanh_sel ? 2.0f * x : x;
  float s = fast_sigmoid(xx);
  return tanh_sel ? 2.0f * s - 1.0f : s;
}
__device__ __forceinline__ float fast_tanh(float x) {
  return 2.0f * fast_sigmoid(2.0f * x) - 1.0f;
}

__device__ __forceinline__ float dpp_xor1(float x) {
  return __int_as_float(__builtin_amdgcn_update_dpp(0, __float_as_int(x), 0xB1, 0xF, 0xF, true));
}
__device__ __forceinline__ float dpp_xor2(float x) {
  return __int_as_float(__builtin_amdgcn_update_dpp(0, __float_as_int(x), 0x4E, 0xF, 0xF, true));
}

// LDS-only barrier: lgkmcnt drain + s_barrier (no vmcnt drain).
__device__ __forceinline__ void bar_lds() {
  __builtin_amdgcn_fence(__ATOMIC_RELEASE, "workgroup", "local");
  __builtin_amdgcn_s_barrier();
  __builtin_amdgcn_fence(__ATOMIC_ACQUIRE, "workgroup", "local");
}

union LD4 {
  float4 f4;
  h2_t h[4];
};

__device__ __forceinline__ unsigned aload(unsigned* p) { return atomicAdd(p, 0u); }

// ---------------------------------------------------------------------------
// Transpose Wx0 [512][128] -> WT [128][512]
// ---------------------------------------------------------------------------
__global__ void wx0_transpose(const float* __restrict__ W, float* __restrict__ WT) {
  int idx = blockIdx.x * 256 + threadIdx.x;
  if (idx < NG * II) {
    int n = idx >> 7;
    int k = idx & 127;
    WT[k * NG + n] = W[idx];
  }
}

// ---------------------------------------------------------------------------
// Xg = x @ Wx0^T + b0, f16, layout [B*T][512]
// ---------------------------------------------------------------------------
__global__ __launch_bounds__(256) void xg0_gemm(const float* __restrict__ X,
                                                const float* __restrict__ WT,
                                                const float* __restrict__ bias,
                                                __half* __restrict__ Xg) {
  __shared__ float As[64][132];
  __shared__ float Bs[128][64];
  const int m0 = blockIdx.x * 64;
  const int n0 = blockIdx.y * 64;
  const int tid = threadIdx.x;

  {
    const float4* xv = (const float4*)(X + (size_t)m0 * II);
#pragma unroll
    for (int r = 0; r < 8; ++r) {
      int f = tid + 256 * r;
      int m = f >> 5;
      int c4 = f & 31;
      float4 v = xv[m * 32 + c4];
      *(float4*)&As[m][c4 * 4] = v;
    }
  }
  {
#pragma unroll
    for (int r = 0; r < 8; ++r) {
      int f = tid + 256 * r;
      int k = f >> 4;
      int q = f & 15;
      float4 v = *(const float4*)(WT + (size_t)k * NG + n0 + q * 4);
      *(float4*)&Bs[k][q * 4] = v;
    }
  }
  __syncthreads();

  const int tx = tid & 15;
  const int ty = tid >> 4;
  float acc[4][4];
#pragma unroll
  for (int i = 0; i < 4; ++i)
#pragma unroll
    for (int j = 0; j < 4; ++j) acc[i][j] = 0.0f;

#pragma unroll 4
  for (int k = 0; k < 128; ++k) {
    float a0 = As[ty * 4 + 0][k];
    float a1 = As[ty * 4 + 1][k];
    float a2 = As[ty * 4 + 2][k];
    float a3 = As[ty * 4 + 3][k];
    float4 bv = *(const float4*)&Bs[k][tx * 4];
    acc[0][0] = fmaf(a0, bv.x, acc[0][0]);
    acc[0][1] = fmaf(a0, bv.y, acc[0][1]);
    acc[0][2] = fmaf(a0, bv.z, acc[0][2]);
    acc[0][3] = fmaf(a0, bv.w, acc[0][3]);
    acc[1][0] = fmaf(a1, bv.x, acc[1][0]);
    acc[1][1] = fmaf(a1, bv.y, acc[1][1]);
    acc[1][2] = fmaf(a1, bv.z, acc[1][2]);
    acc[1][3] = fmaf(a1, bv.w, acc[1][3]);
    acc[2][0] = fmaf(a2, bv.x, acc[2][0]);
    acc[2][1] = fmaf(a2, bv.y, acc[2][1]);
    acc[2][2] = fmaf(a2, bv.z, acc[2][2]);
    acc[2][3] = fmaf(a2, bv.w, acc[2][3]);
    acc[3][0] = fmaf(a3, bv.x, acc[3][0]);
    acc[3][1] = fmaf(a3, bv.y, acc[3][1]);
    acc[3][2] = fmaf(a3, bv.z, acc[3][2]);
    acc[3][3] = fmaf(a3, bv.w, acc[3][3]);
  }

  float4 bvec = *(const float4*)(bias + n0 + tx * 4);
#pragma unroll
  for (int i = 0; i < 4; ++i) {
    int m = m0 + ty * 4 + i;
    __half2* dst = (__half2*)(Xg + (size_t)m * NG + n0 + tx * 4);
    dst[0] = __halves2half2(__float2half(acc[i][0] + bvec.x),
                            __float2half(acc[i][1] + bvec.y));
    dst[1] = __halves2half2(__float2half(acc[i][2] + bvec.z),
                            __float2half(acc[i][3] + bvec.w));
  }
}

// ---------------------------------------------------------------------------
// 2-WG-per-batch layer pipeline. blocks [0,64): role A (layer 0 + Wx1 rows
// [0,256)); blocks [64,128): role B (Wx1 rows [256,512) + layer 1).
// Each WG's weights (96 f16x2 regs/thread) fit the 128-reg arch half ->
// no AGPR copy tax. A->B payload (pg_i, pg_f, h0 as f32 words) via
// device-scope atomics into a 64-slot ring in ws; flag[s]=step+1 after a
// release fence; B prefetches flag/payload one step ahead (latency hidden).
// A throttled every 16 steps against B's progress counter (ring safety).
// ---------------------------------------------------------------------------
__global__
__attribute__((amdgpu_flat_work_group_size(512, 512)))
void lstm_pipe(
    const __half* __restrict__ Xg,    // [B*T][512]
    const float* __restrict__ Wh0,    // [512][128]
    const float* __restrict__ Wx1,    // [512][128]
    const float* __restrict__ Wh1,    // [512][128]
    const float* __restrict__ b1,     // [512]
    float* __restrict__ out,          // output | hT | cT
    unsigned* __restrict__ pay_all,   // [BB][SLOTS][PAYW]
    unsigned* __restrict__ flg_all,   // [BB][SLOTS]
    unsigned* __restrict__ prog_all)  // [BB]
{
  const int role = blockIdx.x >> 6;
  const int b = blockIdx.x & 63;
  const int n = threadIdx.x;
  const int j = n >> 2;
  const int p = n & 3;
  const bool tsel = (p == 2);

  unsigned* pay = pay_all + (size_t)b * SLOTS * PAYW;
  unsigned* flg = flg_all + (size_t)b * SLOTS;
  unsigned* prog = prog_all + b;

  float* outp = out + (size_t)b * TT * HH;
  float* hT = out + (size_t)BB * TT * HH;   // [2][64][128]
  float* cT = hT + 2 * BB * HH;

  if (role == 0) {
    // ================= ROLE A: layer 0 + partial Wx1 (gates i,f) ==========
    h2_t wh[4][16], wxi[16], wxf[16];
#pragma unroll
    for (int g = 0; g < 4; ++g) {
      const float2* ph = (const float2*)(Wh0 + (size_t)(g * 128 + j) * HH + p * 32);
#pragma unroll
      for (int k = 0; k < 16; ++k) {
        float2 v = ph[k];
        wh[g][k][0] = (_Float16)v.x; wh[g][k][1] = (_Float16)v.y;
      }
    }
    {
      const float2* pi = (const float2*)(Wx1 + (size_t)j * HH + p * 32);
      const float2* pf = (const float2*)(Wx1 + (size_t)(128 + j) * HH + p * 32);
#pragma unroll
      for (int k = 0; k < 16; ++k) {
        float2 v;
        v = pi[k]; wxi[k][0] = (_Float16)v.x; wxi[k][1] = (_Float16)v.y;
        v = pf[k]; wxf[k][0] = (_Float16)v.x; wxf[k][1] = (_Float16)v.y;
      }
    }

    __shared__ __align__(16) _Float16 h0b[2][HH];
    if (n < HH) {
      h0b[0][n] = (_Float16)0.0f;
      h0b[1][n] = (_Float16)0.0f;
    }
    float c0 = 0.0f, h0v = 0.0f;
    float zship = 0.0f, h0ship = 0.0f;   // step i-1 values to ship
    __syncthreads();

    const __half* xs = Xg + (size_t)b * TT * NG + p * 128 + j;
    __half xg_c = xs[0];

#pragma unroll 1
    for (int i = 0; i < TT; ++i) {
      // throttle every 16 steps (gate BEFORE shipping into the ring)
      if ((i & 15) == 0) {
        if (n == 0) {
          while ((unsigned)(i + 1) - aload(prog) > 40u) { }
        }
        bar_lds();
      }
      // ship payload(i-1)
      if (i > 0) {
        unsigned* base = pay + (size_t)((i - 1) & (SLOTS - 1)) * PAYW;
        if (p == 0) {
          atomicExch(base + j, __float_as_uint(zship));          // pg_i
          atomicExch(base + 256 + j, __float_as_uint(h0ship));   // h0
        } else if (p == 1) {
          atomicExch(base + 128 + j, __float_as_uint(zship));    // pg_f
        }
      }

      // ---- phase 1: g0(i) ----
      {
        const char* H0 = (const char*)h0b[(i & 1) ^ 1] + p * 64;
        float a0 = 0.f, a1 = 0.f, a2 = 0.f, a3 = 0.f;
#pragma unroll
        for (int q = 0; q < 4; ++q) {
          LD4 u; u.f4 = *(const float4*)(H0 + q * 16);
#pragma unroll
          for (int t = 0; t < 4; ++t) {
            const int m = q * 4 + t;
            a0 = fdot2f(wh[0][m], u.h[t], a0);
            a1 = fdot2f(wh[1][m], u.h[t], a1);
            a2 = fdot2f(wh[2][m], u.h[t], a2);
            a3 = fdot2f(wh[3][m], u.h[t], a3);
          }
        }
        // 4-value reduce-scatter: lane p <- gate p sum
        float k01 = (p & 1) ? a1 : a0;
        float u01 = (p & 1) ? a0 : a1;
        float r01 = k01 + dpp_xor1(u01);
        float k23 = (p & 1) ? a3 : a2;
        float u23 = (p & 1) ? a2 : a3;
        float r23 = k23 + dpp_xor1(u23);
        float kA = (p & 2) ? r23 : r01;
        float uA = (p & 2) ? r01 : r23;
        float sL0 = kA + dpp_xor2(uA);
        float aL0 = act_gate(sL0 + __half2float(xg_c), tsel);
        float f0 = dpp_xor1(aL0);
        float g0v = dpp_xor2(aL0);
        float o0 = dpp_xor2(f0);
        if (p == 0) {
          c0 = f0 * c0 + aL0 * g0v;
          h0v = o0 * fast_tanh(c0);
          h0b[i & 1][j] = (_Float16)h0v;
        }
      }

      // release fence (drains payload atomics), barrier, then flag(i-1)
      __builtin_amdgcn_fence(__ATOMIC_RELEASE, "agent");
      bar_lds();
      if (i > 0 && n == 0) atomicExch(flg + ((i - 1) & (SLOTS - 1)), (unsigned)i);

      // ---- phase 2: partial g1: Wx1 rows {j, 128+j} . h0(i) ----
      {
        const char* H0n = (const char*)h0b[i & 1] + p * 64;
        float pi = 0.f, pf = 0.f;
#pragma unroll
        for (int q = 0; q < 4; ++q) {
          LD4 u; u.f4 = *(const float4*)(H0n + q * 16);
#pragma unroll
          for (int t = 0; t < 4; ++t) {
            const int m = q * 4 + t;
            pi = fdot2f(wxi[m], u.h[t], pi);
            pf = fdot2f(wxf[m], u.h[t], pf);
          }
        }
        // 2-value scatter: lane0 -> pi total, lane1 -> pf total
        float x = (p & 1) ? pf : pi;
        float y = (p & 1) ? pi : pf;
        float t1 = x + dpp_xor1(y);
        zship = t1 + dpp_xor2(t1);
      }
      h0ship = h0v;

      // prefetch xg(i+1) AFTER the fence (so the fence never waits on it)
      if (i + 1 < TT) xg_c = xs[(size_t)(i + 1) * NG];
    }

    // epilogue: ship payload(TT-1)
    {
      unsigned* base = pay + (size_t)((TT - 1) & (SLOTS - 1)) * PAYW;
      if (p == 0) {
        atomicExch(base + j, __float_as_uint(zship));
        atomicExch(base + 256 + j, __float_as_uint(h0ship));
      } else if (p == 1) {
        atomicExch(base + 128 + j, __float_as_uint(zship));
      }
      __builtin_amdgcn_fence(__ATOMIC_RELEASE, "agent");
      bar_lds();
      if (n == 0) atomicExch(flg + ((TT - 1) & (SLOTS - 1)), (unsigned)TT);
    }
    if (p == 0) {
      hT[b * HH + j] = h0v;
      cT[b * HH + j] = c0;
    }
  } else {
    // ================= ROLE B: Wx1 rows [256,512) + layer 1 ===============
    h2_t wxg[16], wxo[16], wv[4][16];
    {
      const float2* pg = (const float2*)(Wx1 + (size_t)(256 + j) * HH + p * 32);
      const float2* po = (const float2*)(Wx1 + (size_t)(384 + j) * HH + p * 32);
#pragma unroll
      for (int k = 0; k < 16; ++k) {
        float2 v;
        v = pg[k]; wxg[k][0] = (_Float16)v.x; wxg[k][1] = (_Float16)v.y;
        v = po[k]; wxo[k][0] = (_Float16)v.x; wxo[k][1] = (_Float16)v.y;
      }
    }
#pragma unroll
    for (int g = 0; g < 4; ++g) {
      const float2* pv = (const float2*)(Wh1 + (size_t)(g * 128 + j) * HH + p * 32);
#pragma unroll
      for (int k = 0; k < 16; ++k) {
        float2 v = pv[k];
        wv[g][k][0] = (_Float16)v.x; wv[g][k][1] = (_Float16)v.y;
      }
    }
    const float bias1 = b1[p * 128 + j];

    __shared__ __align__(16) _Float16 h0B[2][HH];
    __shared__ __align__(16) _Float16 h1b[2][HH];
    __shared__ float pgL[2][256];
    if (n < HH) {
      h1b[0][n] = (_Float16)0.0f;
      h1b[1][n] = (_Float16)0.0f;
    }
    float c1 = 0.0f, h1v = 0.0f;
    __syncthreads();

    // prologue: wait for payload 0, issue its reads, preload flag[1]
    if (n == 0) {
      while (aload(flg + 0) != 1u) { }
    }
    bar_lds();
    unsigned payw = 0, flagval = 0;
    if (n < PAYW) payw = aload(pay + n);
    if (n == 0) flagval = aload(flg + 1);

#pragma unroll 1
    for (int k = 0; k < TT; ++k) {
      const int buf = k & 1;
      // 1. deposit payload[k] into LDS
      if (n < 256) {
        pgL[buf][n] = __uint_as_float(payw);
      } else if (n < PAYW) {
        h0B[buf][n - 256] = (_Float16)__uint_as_float(payw);
      }
      // 2. verify flag[k+1] (preloaded; slow-path poll)
      if (n == 0 && k + 1 < TT) {
        while (flagval != (unsigned)(k + 2)) flagval = aload(flg + ((k + 1) & (SLOTS - 1)));
      }
      // publish progress
      if (n == 0 && (k & 15) == 0) atomicExch(prog, (unsigned)(k + 1));
      // 3. barrier: LDS ready + flag verified
      bar_lds();
      // 4. prefetch payload[k+1] / flag[k+2]
      if (k + 1 < TT) {
        if (n < PAYW) payw = aload(pay + (size_t)((k + 1) & (SLOTS - 1)) * PAYW + n);
        if (n == 0 && k + 2 < TT) flagval = aload(flg + ((k + 2) & (SLOTS - 1)));
      }
      // 5. compute gates1(k) = Wx1.h0(k) + Wh1.h1(k-1) + b1
      {
        const char* H0 = (const char*)h0B[buf] + p * 64;
        const char* H1 = (const char*)h1b[buf] + p * 64;
        float a0 = 0.f, a1 = 0.f, a2 = 0.f, a3 = 0.f, sg = 0.f, so = 0.f;
#pragma unroll
        for (int q = 0; q < 4; ++q) {
          LD4 u0; u0.f4 = *(const float4*)(H0 + q * 16);
          LD4 u1; u1.f4 = *(const float4*)(H1 + q * 16);
#pragma unroll
          for (int t = 0; t < 4; ++t) {
            const int m = q * 4 + t;
            a0 = fdot2f(wv[0][m], u1.h[t], a0);
            a1 = fdot2f(wv[1][m], u1.h[t], a1);
            a2 = fdot2f(wv[2][m], u1.h[t], a2);
            a3 = fdot2f(wv[3][m], u1.h[t], a3);
            sg = fdot2f(wxg[m], u0.h[t], sg);
            so = fdot2f(wxo[m], u0.h[t], so);
          }
        }
        // Wh1 4-value reduce-scatter -> lane p
        float k01 = (p & 1) ? a1 : a0;
        float u01 = (p & 1) ? a0 : a1;
        float r01 = k01 + dpp_xor1(u01);
        float k23 = (p & 1) ? a3 : a2;
        float u23 = (p & 1) ? a2 : a3;
        float r23 = k23 + dpp_xor1(u23);
        float kA = (p & 2) ? r23 : r01;
        float uA = (p & 2) ? r01 : r23;
        float wvp = kA + dpp_xor2(uA);
        // own Wx1 {g,o} 2-value scatter -> lanes 2,3
        float x = (p & 1) ? so : sg;
        float y = (p & 1) ? sg : so;
        float t1 = x + dpp_xor1(y);
        float z = t1 + dpp_xor2(t1);
        float extra = (p < 2) ? pgL[buf][p * 128 + j] : z;
        float aL1 = act_gate(wvp + extra + bias1, tsel);
        float f1 = dpp_xor1(aL1);
        float g1 = dpp_xor2(aL1);
        float o1 = dpp_xor2(f1);
        if (p == 0) {
          c1 = f1 * c1 + aL1 * g1;
          h1v = o1 * fast_tanh(c1);
          h1b[buf ^ 1][j] = (_Float16)h1v;
          outp[(size_t)k * HH + j] = h1v;
        }
      }
    }
    if (p == 0) {
      hT[BB * HH + b * HH + j] = h1v;
      cT[BB * HH + b * HH + j] = c1;
    }
  }
}

// ---------------------------------------------------------------------------
extern "C" void kernel_launch(void* const* d_in, const int* in_sizes, int n_in,
                              void* d_out, int out_size, void* d_ws, size_t ws_size,
                              hipStream_t stream) {
  const float* x   = (const float*)d_in[0];
  const float* Wx0 = (const float*)d_in[1];
  const float* Wh0 = (const float*)d_in[2];
  const float* b0  = (const float*)d_in[3];
  const float* Wx1 = (const float*)d_in[4];
  const float* Wh1 = (const float*)d_in[5];
  const float* b1  = (const float*)d_in[6];
  float* out = (float*)d_out;

  // ws layout: Xg f16 [B*T][512] | WT f32 [128][512] | payload | flags | prog
  char* base = (char*)d_ws;
  __half* Xg = (__half*)base;
  size_t off = (size_t)BB * TT * NG * sizeof(__half);
  float* WT = (float*)(base + off);
  off += (size_t)II * NG * sizeof(float);
  unsigned* pay = (unsigned*)(base + off);
  off += (size_t)BB * SLOTS * PAYW * sizeof(unsigned);
  unsigned* flg = (unsigned*)(base + off);
  size_t flagBytes = (size_t)BB * SLOTS * sizeof(unsigned) + BB * sizeof(unsigned);
  unsigned* prog = flg + BB * SLOTS;

  hipMemsetAsync(flg, 0, flagBytes, stream);
  wx0_transpose<<<(NG * II + 255) / 256, 256, 0, stream>>>(Wx0, WT);
  xg0_gemm<<<dim3((BB * TT) / 64, NG / 64), 256, 0, stream>>>(x, WT, b0, Xg);
  lstm_pipe<<<128, 512, 0, stream>>>(Xg, Wh0, Wx1, Wh1, b1, out, pay, flg, prog);
}

// Round 10
// 2542.839 us; speedup vs baseline: 4.1558x; 4.1558x over previous
//
#include <hip/hip_runtime.h>
#include <hip/hip_fp16.h>

// Problem constants
#define BB 64
#define TT 2048
#define II 128
#define HH 128
#define NG 512  // 4*H

typedef _Float16 h2_t __attribute__((ext_vector_type(2)));

#if defined(__has_builtin)
#if __has_builtin(__builtin_amdgcn_fdot2)
#define HAVE_FDOT2 1
#endif
#endif

__device__ __forceinline__ float fdot2f(h2_t a, h2_t b, float c) {
#ifdef HAVE_FDOT2
  return __builtin_amdgcn_fdot2(a, b, c, false);
#else
  return c + (float)a[0] * (float)b[0] + (float)a[1] * (float)b[1];
#endif
}

__device__ __forceinline__ float fast_sigmoid(float x) {
  float t = __builtin_amdgcn_exp2f(-1.4426950408889634f * x);
  return __builtin_amdgcn_rcpf(1.0f + t);
}
__device__ __forceinline__ float act_gate(float x, bool tanh_sel) {
  float xx = tanh_sel ? 2.0f * x : x;
  float s = fast_sigmoid(xx);
  return tanh_sel ? 2.0f * s - 1.0f : s;
}
__device__ __forceinline__ float fast_tanh(float x) {
  return 2.0f * fast_sigmoid(2.0f * x) - 1.0f;
}

__device__ __forceinline__ float dpp_xor1(float x) {
  return __int_as_float(__builtin_amdgcn_update_dpp(0, __float_as_int(x), 0xB1, 0xF, 0xF, true));
}
__device__ __forceinline__ float dpp_xor2(float x) {
  return __int_as_float(__builtin_amdgcn_update_dpp(0, __float_as_int(x), 0x4E, 0xF, 0xF, true));
}

// LDS-only barrier: lgkmcnt drain + s_barrier (no vmcnt drain).
__device__ __forceinline__ void bar_lds() {
  __builtin_amdgcn_fence(__ATOMIC_RELEASE, "workgroup", "local");
  __builtin_amdgcn_s_barrier();
  __builtin_amdgcn_fence(__ATOMIC_ACQUIRE, "workgroup", "local");
}

union LD4 {
  float4 f4;
  h2_t h[4];
};

// ---------------------------------------------------------------------------
// Transpose W [512][128] -> WT [128][512] (fp32)
// ---------------------------------------------------------------------------
__global__ void w_transpose(const float* __restrict__ W, float* __restrict__ WT) {
  int idx = blockIdx.x * 256 + threadIdx.x;
  if (idx < NG * II) {
    int n = idx >> 7;
    int k = idx & 127;
    WT[k * NG + n] = W[idx];
  }
}

// ---------------------------------------------------------------------------
// Xg = A @ WT + bias  -> f16 [M][512].  A is f32 [M][128] (A16=0) or
// f16 [M][128] (A16=1). BM=64, BN=64, full-K in LDS.
// ---------------------------------------------------------------------------
template <int A16>
__global__ __launch_bounds__(256) void xg_gemm(const void* __restrict__ Ain,
                                               const float* __restrict__ WT,  // [128][512]
                                               const float* __restrict__ bias,
                                               __half* __restrict__ Xg) {   // [M][512]
  __shared__ float As[64][132];
  __shared__ float Bs[128][64];
  const int m0 = blockIdx.x * 64;
  const int n0 = blockIdx.y * 64;
  const int tid = threadIdx.x;

  if (A16) {
    const __half* X = (const __half*)Ain;
#pragma unroll
    for (int r = 0; r < 8; ++r) {
      int f = tid + 256 * r;
      int m = f >> 5;
      int c4 = f & 31;
      const __half2* src = (const __half2*)(X + (size_t)(m0 + m) * II + c4 * 4);
      __half2 v0 = src[0], v1 = src[1];
      As[m][c4 * 4 + 0] = __half2float(v0.x);
      As[m][c4 * 4 + 1] = __half2float(v0.y);
      As[m][c4 * 4 + 2] = __half2float(v1.x);
      As[m][c4 * 4 + 3] = __half2float(v1.y);
    }
  } else {
    const float4* xv = (const float4*)((const float*)Ain + (size_t)m0 * II);
#pragma unroll
    for (int r = 0; r < 8; ++r) {
      int f = tid + 256 * r;
      int m = f >> 5;
      int c4 = f & 31;
      float4 v = xv[m * 32 + c4];
      *(float4*)&As[m][c4 * 4] = v;
    }
  }
  {
#pragma unroll
    for (int r = 0; r < 8; ++r) {
      int f = tid + 256 * r;
      int k = f >> 4;
      int q = f & 15;
      float4 v = *(const float4*)(WT + (size_t)k * NG + n0 + q * 4);
      *(float4*)&Bs[k][q * 4] = v;
    }
  }
  __syncthreads();

  const int tx = tid & 15;
  const int ty = tid >> 4;
  float acc[4][4];
#pragma unroll
  for (int i = 0; i < 4; ++i)
#pragma unroll
    for (int j = 0; j < 4; ++j) acc[i][j] = 0.0f;

#pragma unroll 4
  for (int k = 0; k < 128; ++k) {
    float a0 = As[ty * 4 + 0][k];
    float a1 = As[ty * 4 + 1][k];
    float a2 = As[ty * 4 + 2][k];
    float a3 = As[ty * 4 + 3][k];
    float4 bv = *(const float4*)&Bs[k][tx * 4];
    acc[0][0] = fmaf(a0, bv.x, acc[0][0]);
    acc[0][1] = fmaf(a0, bv.y, acc[0][1]);
    acc[0][2] = fmaf(a0, bv.z, acc[0][2]);
    acc[0][3] = fmaf(a0, bv.w, acc[0][3]);
    acc[1][0] = fmaf(a1, bv.x, acc[1][0]);
    acc[1][1] = fmaf(a1, bv.y, acc[1][1]);
    acc[1][2] = fmaf(a1, bv.z, acc[1][2]);
    acc[1][3] = fmaf(a1, bv.w, acc[1][3]);
    acc[2][0] = fmaf(a2, bv.x, acc[2][0]);
    acc[2][1] = fmaf(a2, bv.y, acc[2][1]);
    acc[2][2] = fmaf(a2, bv.z, acc[2][2]);
    acc[2][3] = fmaf(a2, bv.w, acc[2][3]);
    acc[3][0] = fmaf(a3, bv.x, acc[3][0]);
    acc[3][1] = fmaf(a3, bv.y, acc[3][1]);
    acc[3][2] = fmaf(a3, bv.z, acc[3][2]);
    acc[3][3] = fmaf(a3, bv.w, acc[3][3]);
  }

  float4 bvec = *(const float4*)(bias + n0 + tx * 4);
#pragma unroll
  for (int i = 0; i < 4; ++i) {
    int m = m0 + ty * 4 + i;
    __half2* dst = (__half2*)(Xg + (size_t)m * NG + n0 + tx * 4);
    dst[0] = __halves2half2(__float2half(acc[i][0] + bvec.x),
                            __float2half(acc[i][1] + bvec.y));
    dst[1] = __halves2half2(__float2half(acc[i][2] + bvec.z),
                            __float2half(acc[i][3] + bvec.w));
  }
}

// ---------------------------------------------------------------------------
// Single-layer recurrence. One WG per batch element, 512 threads.
// Thread n = 4j+p owns the 4 gate rows {j,128+j,256+j,384+j} of THIS layer,
// K-quarter p: weights = 64 f16x2 regs/thread -> fits the 128-reg arch half
// of the unified RF -> NO AGPR copy tax (the R5-R8 2.2x VALU inflation).
// Xg (f16, [B*T][512]) already contains the input-side term + bias.
// DPP reduce-scatter -> lane p holds gate p; one activation per lane;
// DPP gathers -> lane 0 updates (c,h) in-register. h double-buffered in LDS,
// ONE barrier per step.
// LAYER==0: writes h-stream (f16) for the bridging GEMM. LAYER==1: writes
// the f32 output. Both write their final h/c into the out tail.
// ---------------------------------------------------------------------------
template <int LAYER>
__global__
__attribute__((amdgpu_flat_work_group_size(512, 512)))
void lstm_layer(
    const __half* __restrict__ Xg,    // [B*T][512]
    const float* __restrict__ Wh,     // [512][128] this layer's recurrent W
    float* __restrict__ out,          // output | hT | cT
    __half* __restrict__ hstream)     // [B*T][128] (written when LAYER==0)
{
  const int b = blockIdx.x;
  const int n = threadIdx.x;
  const int j = n >> 2;
  const int p = n & 3;
  const bool tsel = (p == 2);

  // weights: rows {g*128+j}, K-slice [32p, 32p+32)
  h2_t wh[4][16];
#pragma unroll
  for (int g = 0; g < 4; ++g) {
    const float2* ph = (const float2*)(Wh + (size_t)(g * 128 + j) * HH + p * 32);
#pragma unroll
    for (int k = 0; k < 16; ++k) {
      float2 v = ph[k];
      wh[g][k][0] = (_Float16)v.x;
      wh[g][k][1] = (_Float16)v.y;
    }
  }

  __shared__ __align__(16) _Float16 hb[2][HH];
  if (n < HH) {
    hb[0][n] = (_Float16)0.0f;
    hb[1][n] = (_Float16)0.0f;
  }
  float c = 0.0f, hv = 0.0f;
  __syncthreads();

  const __half* xs = Xg + (size_t)b * TT * NG + p * 128 + j;
  float* outp = out + (size_t)b * TT * HH;
  float* hT = out + (size_t)BB * TT * HH;   // [2][64][128]
  float* cT = hT + 2 * BB * HH;
  __half* hsp = hstream + (size_t)b * TT * HH + j;

  __half xg_c = xs[0];

#pragma unroll 1
  for (int i = 0; i < TT; ++i) {
    const int ip = (i + 1 < TT) ? i + 1 : i;
    __half xg_n = xs[(size_t)ip * NG];   // stays in flight across the barrier

    // ---- 64 dot2: partials of this unit's 4 gate rows ----
    const char* H = (const char*)hb[i & 1] + p * 64;
    float a0 = 0.f, a1 = 0.f, a2 = 0.f, a3 = 0.f;
#pragma unroll
    for (int q = 0; q < 4; ++q) {
      LD4 u;
      u.f4 = *(const float4*)(H + q * 16);
#pragma unroll
      for (int t = 0; t < 4; ++t) {
        const int m = q * 4 + t;
        a0 = fdot2f(wh[0][m], u.h[t], a0);
        a1 = fdot2f(wh[1][m], u.h[t], a1);
        a2 = fdot2f(wh[2][m], u.h[t], a2);
        a3 = fdot2f(wh[3][m], u.h[t], a3);
      }
    }

    // ---- quad reduce-scatter: lane p <- full sum of gate p ----
    float k01 = (p & 1) ? a1 : a0;
    float u01 = (p & 1) ? a0 : a1;
    float r01 = k01 + dpp_xor1(u01);
    float k23 = (p & 1) ? a3 : a2;
    float u23 = (p & 1) ? a2 : a3;
    float r23 = k23 + dpp_xor1(u23);
    float kA = (p & 2) ? r23 : r01;
    float uA = (p & 2) ? r01 : r23;
    float sL = kA + dpp_xor2(uA);

    // ---- one activation per lane (xg already includes bias) ----
    float aL = act_gate(sL + __half2float(xg_c), tsel);

    // ---- gather (i,f,g,o) to lane 0, update cell ----
    float fg = dpp_xor1(aL);
    float gg = dpp_xor2(aL);
    float og = dpp_xor2(fg);

    if (p == 0) {
      c = fg * c + aL * gg;
      hv = og * fast_tanh(c);
      _Float16 hf = (_Float16)hv;
      hb[(i & 1) ^ 1][j] = hf;
      if (LAYER == 0) {
        *(_Float16*)(hsp + (size_t)i * HH) = hf;
      } else {
        outp[(size_t)i * HH + j] = hv;
      }
    }
    bar_lds();
    xg_c = xg_n;
  }

  if (p == 0) {
    hT[LAYER * BB * HH + b * HH + j] = hv;
    cT[LAYER * BB * HH + b * HH + j] = c;
  }
}

// ---------------------------------------------------------------------------
extern "C" void kernel_launch(void* const* d_in, const int* in_sizes, int n_in,
                              void* d_out, int out_size, void* d_ws, size_t ws_size,
                              hipStream_t stream) {
  const float* x   = (const float*)d_in[0];
  const float* Wx0 = (const float*)d_in[1];
  const float* Wh0 = (const float*)d_in[2];
  const float* b0  = (const float*)d_in[3];
  const float* Wx1 = (const float*)d_in[4];
  const float* Wh1 = (const float*)d_in[5];
  const float* b1  = (const float*)d_in[6];
  float* out = (float*)d_out;

  // ws layout: XgBuf f16 [B*T][512] (Xg0, later overwritten by Xg1) |
  //            hstream f16 [B*T][128] | WT0 f32 [128][512] | WT1 f32
  char* base = (char*)d_ws;
  __half* XgBuf = (__half*)base;
  size_t off = (size_t)BB * TT * NG * sizeof(__half);      // 128 MB
  __half* hstream = (__half*)(base + off);
  off += (size_t)BB * TT * HH * sizeof(__half);            // +32 MB
  float* WT0 = (float*)(base + off);
  off += (size_t)II * NG * sizeof(float);
  float* WT1 = (float*)(base + off);

  const int tgrid = (NG * II + 255) / 256;
  w_transpose<<<tgrid, 256, 0, stream>>>(Wx0, WT0);
  w_transpose<<<tgrid, 256, 0, stream>>>(Wx1, WT1);

  dim3 ggrid((BB * TT) / 64, NG / 64);
  // Pass 1: Xg0 = x @ Wx0^T + b0, then L0 recurrence (writes hstream)
  xg_gemm<0><<<ggrid, 256, 0, stream>>>(x, WT0, b0, XgBuf);
  lstm_layer<0><<<BB, 512, 0, stream>>>(XgBuf, Wh0, out, hstream);
  // Pass 2: Xg1 = h0 @ Wx1^T + b1 (overwrites XgBuf; Xg0 fully consumed)
  xg_gemm<1><<<ggrid, 256, 0, stream>>>(hstream, WT1, b1, XgBuf);
  // Pass 3: L1 recurrence (writes output)
  lstm_layer<1><<<BB, 512, 0, stream>>>(XgBuf, Wh1, out, hstream);
}

// Round 11
// 1537.721 us; speedup vs baseline: 6.8722x; 1.6536x over previous
//
#include <hip/hip_runtime.h>
#include <hip/hip_fp16.h>

// Problem constants
#define BB 64
#define TT 2048
#define II 128
#define HH 128
#define NG 512   // 4*H
#define CH 128   // pipeline chunk (steps)
#define NCH (TT / CH)

typedef _Float16 h2_t __attribute__((ext_vector_type(2)));

#if defined(__has_builtin)
#if __has_builtin(__builtin_amdgcn_fdot2)
#define HAVE_FDOT2 1
#endif
#endif

__device__ __forceinline__ float fdot2f(h2_t a, h2_t b, float c) {
#ifdef HAVE_FDOT2
  return __builtin_amdgcn_fdot2(a, b, c, false);
#else
  return c + (float)a[0] * (float)b[0] + (float)a[1] * (float)b[1];
#endif
}

__device__ __forceinline__ float fast_sigmoid(float x) {
  float t = __builtin_amdgcn_exp2f(-1.4426950408889634f * x);
  return __builtin_amdgcn_rcpf(1.0f + t);
}
__device__ __forceinline__ float act_gate(float x, bool tanh_sel) {
  float xx = tanh_sel ? 2.0f * x : x;
  float s = fast_sigmoid(xx);
  return tanh_sel ? 2.0f * s - 1.0f : s;
}
__device__ __forceinline__ float fast_tanh(float x) {
  return 2.0f * fast_sigmoid(2.0f * x) - 1.0f;
}

__device__ __forceinline__ float dpp_xor1(float x) {
  return __int_as_float(__builtin_amdgcn_update_dpp(0, __float_as_int(x), 0xB1, 0xF, 0xF, true));
}
__device__ __forceinline__ float dpp_xor2(float x) {
  return __int_as_float(__builtin_amdgcn_update_dpp(0, __float_as_int(x), 0x4E, 0xF, 0xF, true));
}

// LDS-only barrier: lgkmcnt drain + s_barrier (no vmcnt drain).
__device__ __forceinline__ void bar_lds() {
  __builtin_amdgcn_fence(__ATOMIC_RELEASE, "workgroup", "local");
  __builtin_amdgcn_s_barrier();
  __builtin_amdgcn_fence(__ATOMIC_ACQUIRE, "workgroup", "local");
}

union LD4 {
  float4 f4;
  h2_t h[4];
};
union LDB {
  uint4 u4;
  h2_t h[4];
};

__device__ __forceinline__ unsigned aload(unsigned* p) { return atomicAdd(p, 0u); }

// ---------------------------------------------------------------------------
// Transpose W [512][128] -> WT [128][512] (fp32)
// ---------------------------------------------------------------------------
__global__ void w_transpose(const float* __restrict__ W, float* __restrict__ WT) {
  int idx = blockIdx.x * 256 + threadIdx.x;
  if (idx < NG * II) {
    int n = idx >> 7;
    int k = idx & 127;
    WT[k * NG + n] = W[idx];
  }
}

// ---------------------------------------------------------------------------
// Xg0 = x @ Wx0^T + b0 -> f16 [B*T][512] (upfront, fully parallel)
// ---------------------------------------------------------------------------
__global__ __launch_bounds__(256) void xg_gemm(const float* __restrict__ X,
                                               const float* __restrict__ WT,
                                               const float* __restrict__ bias,
                                               __half* __restrict__ Xg) {
  __shared__ float As[64][132];
  __shared__ float Bs[128][64];
  const int m0 = blockIdx.x * 64;
  const int n0 = blockIdx.y * 64;
  const int tid = threadIdx.x;

  {
    const float4* xv = (const float4*)(X + (size_t)m0 * II);
#pragma unroll
    for (int r = 0; r < 8; ++r) {
      int f = tid + 256 * r;
      int m = f >> 5;
      int c4 = f & 31;
      float4 v = xv[m * 32 + c4];
      *(float4*)&As[m][c4 * 4] = v;
    }
  }
  {
#pragma unroll
    for (int r = 0; r < 8; ++r) {
      int f = tid + 256 * r;
      int k = f >> 4;
      int q = f & 15;
      float4 v = *(const float4*)(WT + (size_t)k * NG + n0 + q * 4);
      *(float4*)&Bs[k][q * 4] = v;
    }
  }
  __syncthreads();

  const int tx = tid & 15;
  const int ty = tid >> 4;
  float acc[4][4];
#pragma unroll
  for (int i = 0; i < 4; ++i)
#pragma unroll
    for (int j = 0; j < 4; ++j) acc[i][j] = 0.0f;

#pragma unroll 4
  for (int k = 0; k < 128; ++k) {
    float a0 = As[ty * 4 + 0][k];
    float a1 = As[ty * 4 + 1][k];
    float a2 = As[ty * 4 + 2][k];
    float a3 = As[ty * 4 + 3][k];
    float4 bv = *(const float4*)&Bs[k][tx * 4];
    acc[0][0] = fmaf(a0, bv.x, acc[0][0]);
    acc[0][1] = fmaf(a0, bv.y, acc[0][1]);
    acc[0][2] = fmaf(a0, bv.z, acc[0][2]);
    acc[0][3] = fmaf(a0, bv.w, acc[0][3]);
    acc[1][0] = fmaf(a1, bv.x, acc[1][0]);
    acc[1][1] = fmaf(a1, bv.y, acc[1][1]);
    acc[1][2] = fmaf(a1, bv.z, acc[1][2]);
    acc[1][3] = fmaf(a1, bv.w, acc[1][3]);
    acc[2][0] = fmaf(a2, bv.x, acc[2][0]);
    acc[2][1] = fmaf(a2, bv.y, acc[2][1]);
    acc[2][2] = fmaf(a2, bv.z, acc[2][2]);
    acc[2][3] = fmaf(a2, bv.w, acc[2][3]);
    acc[3][0] = fmaf(a3, bv.x, acc[3][0]);
    acc[3][1] = fmaf(a3, bv.y, acc[3][1]);
    acc[3][2] = fmaf(a3, bv.z, acc[3][2]);
    acc[3][3] = fmaf(a3, bv.w, acc[3][3]);
  }

  float4 bvec = *(const float4*)(bias + n0 + tx * 4);
#pragma unroll
  for (int i = 0; i < 4; ++i) {
    int m = m0 + ty * 4 + i;
    __half2* dst = (__half2*)(Xg + (size_t)m * NG + n0 + tx * 4);
    dst[0] = __halves2half2(__float2half(acc[i][0] + bvec.x),
                            __float2half(acc[i][1] + bvec.y));
    dst[1] = __halves2half2(__float2half(acc[i][2] + bvec.z),
                            __float2half(acc[i][3] + bvec.w));
  }
}

// ===========================================================================
// Mega kernel: 256 WGs.
//   [0,64):    role A — L0 recurrence, writes hstream, flag0 per chunk
//   [64,192):  role C — 2 WGs/batch, chunk GEMM Xg1 = h0 @ Wx1^T + b1
//              (overwrites the CONSUMED part of Xg in place), flagC
//   [192,256): role B — L1 recurrence on Xg1 chunks, writes output
// Chunk-level flags only (16 per batch) with agent-scope fences.
// ===========================================================================

// ---- role A: layer-0 recurrence (identical math to R10, + chunk flags) ----
__device__ __forceinline__ void roleA(int b, int n, char* smem,
    const __half* Xg, const float* __restrict__ Wh0,
    float* __restrict__ out, __half* hstream, unsigned* flag0)
{
  const int j = n >> 2;
  const int p = n & 3;
  const bool tsel = (p == 2);

  h2_t wh[4][16];
#pragma unroll
  for (int g = 0; g < 4; ++g) {
    const float2* ph = (const float2*)(Wh0 + (size_t)(g * 128 + j) * HH + p * 32);
#pragma unroll
    for (int k = 0; k < 16; ++k) {
      float2 v = ph[k];
      wh[g][k][0] = (_Float16)v.x;
      wh[g][k][1] = (_Float16)v.y;
    }
  }

  _Float16(*hb)[HH] = (_Float16(*)[HH])smem;
  if (n < HH) {
    hb[0][n] = (_Float16)0.0f;
    hb[1][n] = (_Float16)0.0f;
  }
  float c = 0.0f, hv = 0.0f;
  __syncthreads();

  const __half* xs = Xg + (size_t)b * TT * NG + p * 128 + j;
  float* hT = out + (size_t)BB * TT * HH;
  float* cT = hT + 2 * BB * HH;
  __half* hsp = hstream + (size_t)b * TT * HH + j;

  __half xg_c = xs[0];

#pragma unroll 1
  for (int cc = 0; cc < NCH; ++cc) {
#pragma unroll 1
    for (int s = 0; s < CH; ++s) {
      const int i = cc * CH + s;
      const int ip = (i + 1 < TT) ? i + 1 : i;
      __half xg_n = xs[(size_t)ip * NG];

      const char* H = (const char*)hb[i & 1] + p * 64;
      float a0 = 0.f, a1 = 0.f, a2 = 0.f, a3 = 0.f;
#pragma unroll
      for (int q = 0; q < 4; ++q) {
        LD4 u;
        u.f4 = *(const float4*)(H + q * 16);
#pragma unroll
        for (int t = 0; t < 4; ++t) {
          const int m = q * 4 + t;
          a0 = fdot2f(wh[0][m], u.h[t], a0);
          a1 = fdot2f(wh[1][m], u.h[t], a1);
          a2 = fdot2f(wh[2][m], u.h[t], a2);
          a3 = fdot2f(wh[3][m], u.h[t], a3);
        }
      }
      float k01 = (p & 1) ? a1 : a0;
      float u01 = (p & 1) ? a0 : a1;
      float r01 = k01 + dpp_xor1(u01);
      float k23 = (p & 1) ? a3 : a2;
      float u23 = (p & 1) ? a2 : a3;
      float r23 = k23 + dpp_xor1(u23);
      float kA = (p & 2) ? r23 : r01;
      float uA = (p & 2) ? r01 : r23;
      float sL = kA + dpp_xor2(uA);
      float aL = act_gate(sL + __half2float(xg_c), tsel);
      float fg = dpp_xor1(aL);
      float gg = dpp_xor2(aL);
      float og = dpp_xor2(fg);
      if (p == 0) {
        c = fg * c + aL * gg;
        hv = og * fast_tanh(c);
        _Float16 hf = (_Float16)hv;
        hb[(i & 1) ^ 1][j] = hf;
        *(_Float16*)(hsp + (size_t)i * HH) = hf;
      }
      bar_lds();
      xg_c = xg_n;
    }
    __syncthreads();   // drains hstream stores (vmcnt)
    if (n == 0) {
      __builtin_amdgcn_fence(__ATOMIC_RELEASE, "agent");
      atomicExch(flag0 + b * NCH + cc, 1u);
    }
  }

  if (p == 0) {
    hT[b * HH + j] = hv;
    cT[b * HH + j] = c;
  }
}

// ---- role C: chunk GEMM Xg1(chunk) = h0(chunk) @ Wx1^T + b1 (f16 dot2) ----
__device__ __forceinline__ void roleC(int cidx, int n, char* smem,
    __half* Xg, const __half* hstream, const float* __restrict__ WT1,
    const float* __restrict__ b1, unsigned* flag0, unsigned* flagC)
{
  const int b = cidx >> 1;
  const int half = cidx & 1;
  h2_t(*As2)[68] = (h2_t(*)[68])smem;                    // [64][68] h2 = 17408B
  h2_t(*Bs2)[64] = (h2_t(*)[64])(smem + 64 * 68 * 4);    // [64][64] h2 = 16384B

  const int ty = n >> 4;   // 0..31 -> rows ty*2, ty*2+1
  const int tx = n & 15;   // cols tx*4..+3 within tile

#pragma unroll 1
  for (int cc = 0; cc < NCH; ++cc) {
    if (n == 0) {
      while (aload(flag0 + b * NCH + cc) < 1u) __builtin_amdgcn_s_sleep(1);
    }
    __syncthreads();
    __builtin_amdgcn_fence(__ATOMIC_ACQUIRE, "agent");

    const int t0 = cc * CH + half * 64;
    // fill As2: 64 rows x 128 k of h0 (raw f16 copy, natural (2k,2k+1) pairs)
    {
      const int m = n >> 3, seg = n & 7;
      const uint4* src = (const uint4*)(hstream + ((size_t)b * TT + t0 + m) * HH + seg * 16);
      uint4 v0 = src[0], v1 = src[1];
      *(uint4*)&As2[m][seg * 8] = v0;
      *(uint4*)&As2[m][seg * 8 + 4] = v1;
    }

#pragma unroll 1
    for (int nt = 0; nt < 8; ++nt) {     // 8 column tiles of 64
      __syncthreads();
      // fill Bs2: Wx1^T cols [nt*64, nt*64+64), k-pairs packed as h2
      {
        const int kp = n >> 3, cg = n & 7;
        const float4* w0 = (const float4*)(WT1 + (size_t)(2 * kp) * NG + nt * 64 + cg * 8);
        const float4* w1 = (const float4*)(WT1 + (size_t)(2 * kp + 1) * NG + nt * 64 + cg * 8);
        float4 x0 = w0[0], x1 = w0[1];
        float4 y0 = w1[0], y1 = w1[1];
        h2_t r[8];
        r[0][0] = (_Float16)x0.x; r[0][1] = (_Float16)y0.x;
        r[1][0] = (_Float16)x0.y; r[1][1] = (_Float16)y0.y;
        r[2][0] = (_Float16)x0.z; r[2][1] = (_Float16)y0.z;
        r[3][0] = (_Float16)x0.w; r[3][1] = (_Float16)y0.w;
        r[4][0] = (_Float16)x1.x; r[4][1] = (_Float16)y1.x;
        r[5][0] = (_Float16)x1.y; r[5][1] = (_Float16)y1.y;
        r[6][0] = (_Float16)x1.z; r[6][1] = (_Float16)y1.z;
        r[7][0] = (_Float16)x1.w; r[7][1] = (_Float16)y1.w;
        *(uint4*)&Bs2[kp][cg * 8] = *(uint4*)&r[0];
        *(uint4*)&Bs2[kp][cg * 8 + 4] = *(uint4*)&r[4];
      }
      __syncthreads();

      float acc[2][4];
#pragma unroll
      for (int r = 0; r < 2; ++r)
#pragma unroll
        for (int q = 0; q < 4; ++q) acc[r][q] = 0.0f;

#pragma unroll 4
      for (int k4 = 0; k4 < 16; ++k4) {
        LDB ua0, ua1;
        ua0.u4 = *(const uint4*)&As2[ty * 2][k4 * 4];
        ua1.u4 = *(const uint4*)&As2[ty * 2 + 1][k4 * 4];
#pragma unroll
        for (int t = 0; t < 4; ++t) {
          LDB ub;
          ub.u4 = *(const uint4*)&Bs2[k4 * 4 + t][tx * 4];
          acc[0][0] = fdot2f(ua0.h[t], ub.h[0], acc[0][0]);
          acc[0][1] = fdot2f(ua0.h[t], ub.h[1], acc[0][1]);
          acc[0][2] = fdot2f(ua0.h[t], ub.h[2], acc[0][2]);
          acc[0][3] = fdot2f(ua0.h[t], ub.h[3], acc[0][3]);
          acc[1][0] = fdot2f(ua1.h[t], ub.h[0], acc[1][0]);
          acc[1][1] = fdot2f(ua1.h[t], ub.h[1], acc[1][1]);
          acc[1][2] = fdot2f(ua1.h[t], ub.h[2], acc[1][2]);
          acc[1][3] = fdot2f(ua1.h[t], ub.h[3], acc[1][3]);
        }
      }

      const int col = nt * 64 + tx * 4;
      float4 bv = *(const float4*)(b1 + col);
#pragma unroll
      for (int r = 0; r < 2; ++r) {
        __half2* d = (__half2*)(Xg + ((size_t)b * TT + t0 + ty * 2 + r) * NG + col);
        d[0] = __halves2half2(__float2half(acc[r][0] + bv.x),
                              __float2half(acc[r][1] + bv.y));
        d[1] = __halves2half2(__float2half(acc[r][2] + bv.z),
                              __float2half(acc[r][3] + bv.w));
      }
    }
    __syncthreads();   // drain Xg1 stores
    if (n == 0) {
      __builtin_amdgcn_fence(__ATOMIC_RELEASE, "agent");
      atomicAdd(flagC + b * NCH + cc, 1u);
    }
  }
}

// ---- role B: layer-1 recurrence on Xg1 chunks ----
__device__ __forceinline__ void roleB(int b, int n, char* smem,
    const __half* Xg, const float* __restrict__ Wh1,
    float* __restrict__ out, unsigned* flagC)
{
  const int j = n >> 2;
  const int p = n & 3;
  const bool tsel = (p == 2);

  h2_t wh[4][16];
#pragma unroll
  for (int g = 0; g < 4; ++g) {
    const float2* ph = (const float2*)(Wh1 + (size_t)(g * 128 + j) * HH + p * 32);
#pragma unroll
    for (int k = 0; k < 16; ++k) {
      float2 v = ph[k];
      wh[g][k][0] = (_Float16)v.x;
      wh[g][k][1] = (_Float16)v.y;
    }
  }

  _Float16(*hb)[HH] = (_Float16(*)[HH])smem;
  if (n < HH) {
    hb[0][n] = (_Float16)0.0f;
    hb[1][n] = (_Float16)0.0f;
  }
  float c = 0.0f, hv = 0.0f;
  __syncthreads();

  const __half* xs = Xg + (size_t)b * TT * NG + p * 128 + j;
  float* outp = out + (size_t)b * TT * HH;
  float* hT = out + (size_t)BB * TT * HH;
  float* cT = hT + 2 * BB * HH;

#pragma unroll 1
  for (int cc = 0; cc < NCH; ++cc) {
    if (n == 0) {
      while (aload(flagC + b * NCH + cc) < 2u) __builtin_amdgcn_s_sleep(1);
    }
    __syncthreads();
    __builtin_amdgcn_fence(__ATOMIC_ACQUIRE, "agent");

    __half xg_c = xs[(size_t)(cc * CH) * NG];
#pragma unroll 1
    for (int s = 0; s < CH; ++s) {
      const int i = cc * CH + s;
      __half xg_n = (s + 1 < CH) ? xs[(size_t)(i + 1) * NG] : __float2half(0.0f);

      const char* H = (const char*)hb[i & 1] + p * 64;
      float a0 = 0.f, a1 = 0.f, a2 = 0.f, a3 = 0.f;
#pragma unroll
      for (int q = 0; q < 4; ++q) {
        LD4 u;
        u.f4 = *(const float4*)(H + q * 16);
#pragma unroll
        for (int t = 0; t < 4; ++t) {
          const int m = q * 4 + t;
          a0 = fdot2f(wh[0][m], u.h[t], a0);
          a1 = fdot2f(wh[1][m], u.h[t], a1);
          a2 = fdot2f(wh[2][m], u.h[t], a2);
          a3 = fdot2f(wh[3][m], u.h[t], a3);
        }
      }
      float k01 = (p & 1) ? a1 : a0;
      float u01 = (p & 1) ? a0 : a1;
      float r01 = k01 + dpp_xor1(u01);
      float k23 = (p & 1) ? a3 : a2;
      float u23 = (p & 1) ? a2 : a3;
      float r23 = k23 + dpp_xor1(u23);
      float kA = (p & 2) ? r23 : r01;
      float uA = (p & 2) ? r01 : r23;
      float sL = kA + dpp_xor2(uA);
      float aL = act_gate(sL + __half2float(xg_c), tsel);
      float fg = dpp_xor1(aL);
      float gg = dpp_xor2(aL);
      float og = dpp_xor2(fg);
      if (p == 0) {
        c = fg * c + aL * gg;
        hv = og * fast_tanh(c);
        hb[(i & 1) ^ 1][j] = (_Float16)hv;
        outp[(size_t)i * HH + j] = hv;
      }
      bar_lds();
      xg_c = xg_n;
    }
  }

  if (p == 0) {
    hT[BB * HH + b * HH + j] = hv;
    cT[BB * HH + b * HH + j] = c;
  }
}

__global__
__attribute__((amdgpu_flat_work_group_size(512, 512)))
void lstm_mega(__half* Xg,              // [B*T][512]: Xg0 in, Xg1 in place
               __half* hstream,         // [B*T][128]
               const float* __restrict__ Wh0,
               const float* __restrict__ Wh1,
               const float* __restrict__ WT1,
               const float* __restrict__ b1,
               float* __restrict__ out,
               unsigned* flag0, unsigned* flagC)
{
  __shared__ __align__(16) char smem[64 * 68 * 4 + 64 * 64 * 4];  // 33792B
  const int bid = blockIdx.x;
  const int n = threadIdx.x;
  if (bid < BB) {
    roleA(bid, n, smem, Xg, Wh0, out, hstream, flag0);
  } else if (bid < BB + 2 * BB) {
    roleC(bid - BB, n, smem, Xg, hstream, WT1, b1, flag0, flagC);
  } else {
    roleB(bid - 3 * BB, n, smem, Xg, Wh1, out, flagC);
  }
}

// ---------------------------------------------------------------------------
extern "C" void kernel_launch(void* const* d_in, const int* in_sizes, int n_in,
                              void* d_out, int out_size, void* d_ws, size_t ws_size,
                              hipStream_t stream) {
  const float* x   = (const float*)d_in[0];
  const float* Wx0 = (const float*)d_in[1];
  const float* Wh0 = (const float*)d_in[2];
  const float* b0  = (const float*)d_in[3];
  const float* Wx1 = (const float*)d_in[4];
  const float* Wh1 = (const float*)d_in[5];
  const float* b1  = (const float*)d_in[6];
  float* out = (float*)d_out;

  // ws: Xg f16 [B*T][512] | hstream f16 [B*T][128] | WT0 | WT1 | flag0 | flagC
  char* base = (char*)d_ws;
  __half* Xg = (__half*)base;
  size_t off = (size_t)BB * TT * NG * sizeof(__half);      // 128 MB
  __half* hstream = (__half*)(base + off);
  off += (size_t)BB * TT * HH * sizeof(__half);            // +32 MB
  float* WT0 = (float*)(base + off);
  off += (size_t)II * NG * sizeof(float);
  float* WT1 = (float*)(base + off);
  off += (size_t)II * NG * sizeof(float);
  unsigned* flag0 = (unsigned*)(base + off);
  off += (size_t)BB * NCH * sizeof(unsigned);
  unsigned* flagC = (unsigned*)(base + off);

  hipMemsetAsync(flag0, 0, 2 * (size_t)BB * NCH * sizeof(unsigned), stream);
  const int tgrid = (NG * II + 255) / 256;
  w_transpose<<<tgrid, 256, 0, stream>>>(Wx0, WT0);
  w_transpose<<<tgrid, 256, 0, stream>>>(Wx1, WT1);
  xg_gemm<<<dim3((BB * TT) / 64, NG / 64), 256, 0, stream>>>(x, WT0, b0, Xg);
  lstm_mega<<<4 * BB, 512, 0, stream>>>(Xg, hstream, Wh0, Wh1, WT1, b1, out,
                                        flag0, flagC);
}